// Round 3
// baseline (283.296 us; speedup 1.0000x reference)
//
#include <hip/hip_runtime.h>
#include <math.h>

// BettingLoss: B x T (T=6) float32 inputs:
//   d_in[0] = predicted_probs, d_in[1] = true_winners, d_in[2] = market_odds
// Outputs (float32 x 3): loss, batch_profit, num_bets
//
// 2 rows = 12 floats = 48 B = 3x float4 per array per thread.
// Round-3 levers: nontemporal (nt) loads to stream past caches + 2x unroll
// with all 18 dwordx4 loads hoisted ahead of consumption (more misses in
// flight per wave; the r1/r2 evidence says we're concurrency-bound, not
// BW- or issue-bound).

constexpr int T = 6;
constexpr int NBLK = 2048;
constexpr int NTHR = 256;

typedef float f4 __attribute__((ext_vector_type(4)));

__device__ __forceinline__ f4 ntload(const f4* p) {
    return __builtin_nontemporal_load(p);
}

__global__ __launch_bounds__(NTHR) void betting_stage1(
    const f4* __restrict__ probs,
    const f4* __restrict__ winners,
    const f4* __restrict__ odds,
    double* __restrict__ partials,   // [NBLK][4]: sum_bet_ep, sum_profit, sum_maxp, count
    int npairs)                      // B/2
{
    const float ALPHA = 1.1f;
    const float BET = 0.02f;
    const float KEEP = 0.95f;            // 1 - commission
    const float PS = BET * KEEP;         // payout_scale

    double s_ep = 0.0, s_profit = 0.0, s_maxp = 0.0;
    int cnt = 0;

    auto do_pair = [&](f4 pa, f4 pb, f4 pc, f4 oa, f4 ob, f4 oc,
                       f4 wa, f4 wb, f4 wc) {
        float p[12] = {pa.x, pa.y, pa.z, pa.w, pb.x, pb.y, pb.z, pb.w, pc.x, pc.y, pc.z, pc.w};
        float o[12] = {oa.x, oa.y, oa.z, oa.w, ob.x, ob.y, ob.z, ob.w, oc.x, oc.y, oc.z, oc.w};
        float w[12] = {wa.x, wa.y, wa.z, wa.w, wb.x, wb.y, wb.z, wb.w, wc.x, wc.y, wc.z, wc.w};
        #pragma unroll
        for (int rr = 0; rr < 2; ++rr) {
            const int off = rr * T;
            bool valid = false;
            float maxp = p[off];
            float best_ep = -INFINITY;
            float best_odds = 0.0f, best_win = 0.0f;
            #pragma unroll
            for (int j = 0; j < T; ++j) {
                const float oj = o[off + j];
                const float pj = p[off + j];
                valid |= (oj > 0.0f);
                maxp = fmaxf(maxp, pj);
                const float ep = (oj * ALPHA * pj - 1.0f) * PS;   // first-max argmax
                if (ep > best_ep) { best_ep = ep; best_odds = oj; best_win = w[off + j]; }
            }
            s_maxp += (double)maxp;
            const bool bet = valid && (best_ep > 0.0f);
            s_ep += bet ? (double)best_ep : 0.0;
            cnt += bet ? 1 : 0;
            const float profit = (best_win > 0.5f)
                ? (best_odds * ALPHA * BET - BET) * KEEP
                : -BET * KEEP;
            s_profit += bet ? (double)profit : 0.0;
        }
    };

    const int stride = gridDim.x * blockDim.x;
    int i = blockIdx.x * blockDim.x + threadIdx.x;

    // 2x-unrolled main loop: 18 nt loads issued before any consumption.
    for (; i + stride < npairs; i += 2 * stride) {
        const size_t b0 = (size_t)i * 3;
        const size_t b1 = (size_t)(i + stride) * 3;
        f4 pa0 = ntload(probs + b0),     pb0 = ntload(probs + b0 + 1), pc0 = ntload(probs + b0 + 2);
        f4 oa0 = ntload(odds  + b0),     ob0 = ntload(odds  + b0 + 1), oc0 = ntload(odds  + b0 + 2);
        f4 wa0 = ntload(winners + b0),   wb0 = ntload(winners + b0 + 1), wc0 = ntload(winners + b0 + 2);
        f4 pa1 = ntload(probs + b1),     pb1 = ntload(probs + b1 + 1), pc1 = ntload(probs + b1 + 2);
        f4 oa1 = ntload(odds  + b1),     ob1 = ntload(odds  + b1 + 1), oc1 = ntload(odds  + b1 + 2);
        f4 wa1 = ntload(winners + b1),   wb1 = ntload(winners + b1 + 1), wc1 = ntload(winners + b1 + 2);
        do_pair(pa0, pb0, pc0, oa0, ob0, oc0, wa0, wb0, wc0);
        do_pair(pa1, pb1, pc1, oa1, ob1, oc1, wa1, wb1, wc1);
    }
    // tail
    for (; i < npairs; i += stride) {
        const size_t b = (size_t)i * 3;
        f4 pa = ntload(probs + b),   pb = ntload(probs + b + 1), pc = ntload(probs + b + 2);
        f4 oa = ntload(odds  + b),   ob = ntload(odds  + b + 1), oc = ntload(odds  + b + 2);
        f4 wa = ntload(winners + b), wb = ntload(winners + b + 1), wc = ntload(winners + b + 2);
        do_pair(pa, pb, pc, oa, ob, oc, wa, wb, wc);
    }

    // wave(64) reduction
    #pragma unroll
    for (int off = 32; off > 0; off >>= 1) {
        s_ep     += __shfl_down(s_ep, off);
        s_profit += __shfl_down(s_profit, off);
        s_maxp   += __shfl_down(s_maxp, off);
        cnt      += __shfl_down(cnt, off);
    }

    __shared__ double sm_ep[NTHR / 64];
    __shared__ double sm_pr[NTHR / 64];
    __shared__ double sm_mx[NTHR / 64];
    __shared__ int    sm_ct[NTHR / 64];
    const int lane = threadIdx.x & 63;
    const int wid  = threadIdx.x >> 6;
    if (lane == 0) {
        sm_ep[wid] = s_ep; sm_pr[wid] = s_profit; sm_mx[wid] = s_maxp; sm_ct[wid] = cnt;
    }
    __syncthreads();
    if (threadIdx.x == 0) {
        double t_ep = 0.0, t_pr = 0.0, t_mx = 0.0; int t_ct = 0;
        #pragma unroll
        for (int k = 0; k < NTHR / 64; ++k) {
            t_ep += sm_ep[k]; t_pr += sm_pr[k]; t_mx += sm_mx[k]; t_ct += sm_ct[k];
        }
        double* slot = partials + (size_t)blockIdx.x * 4;
        slot[0] = t_ep; slot[1] = t_pr; slot[2] = t_mx; slot[3] = (double)t_ct;
    }
}

__global__ __launch_bounds__(NTHR) void betting_stage2(
    const double* __restrict__ partials, float* __restrict__ out, int nblk, int B)
{
    double s_ep = 0.0, s_pr = 0.0, s_mx = 0.0, s_ct = 0.0;
    for (int i = threadIdx.x; i < nblk; i += blockDim.x) {
        const double* slot = partials + (size_t)i * 4;
        s_ep += slot[0]; s_pr += slot[1]; s_mx += slot[2]; s_ct += slot[3];
    }
    #pragma unroll
    for (int off = 32; off > 0; off >>= 1) {
        s_ep += __shfl_down(s_ep, off);
        s_pr += __shfl_down(s_pr, off);
        s_mx += __shfl_down(s_mx, off);
        s_ct += __shfl_down(s_ct, off);
    }
    __shared__ double sm[4][NTHR / 64];
    const int lane = threadIdx.x & 63;
    const int wid  = threadIdx.x >> 6;
    if (lane == 0) { sm[0][wid] = s_ep; sm[1][wid] = s_pr; sm[2][wid] = s_mx; sm[3][wid] = s_ct; }
    __syncthreads();
    if (threadIdx.x == 0) {
        double ep = 0.0, pr = 0.0, mx = 0.0, ct = 0.0;
        #pragma unroll
        for (int k = 0; k < NTHR / 64; ++k) { ep += sm[0][k]; pr += sm[1][k]; mx += sm[2][k]; ct += sm[3][k]; }
        bool any_bet = ct > 0.0;
        double total = any_bet ? ep : (-(mx / (double)B) * 0.1);
        out[0] = (float)(-total / (double)B);
        out[1] = (float)pr;
        out[2] = (float)ct;
    }
}

extern "C" void kernel_launch(void* const* d_in, const int* in_sizes, int n_in,
                              void* d_out, int out_size, void* d_ws, size_t ws_size,
                              hipStream_t stream) {
    const float* probs   = (const float*)d_in[0];
    const float* winners = (const float*)d_in[1];
    const float* odds    = (const float*)d_in[2];
    float* out = (float*)d_out;
    const int B = in_sizes[0] / T;
    const int npairs = B / 2;   // B = 4194304, even

    double* partials = (double*)d_ws;   // NBLK * 4 doubles = 64 KiB; every slot written each call

    betting_stage1<<<NBLK, NTHR, 0, stream>>>(
        (const f4*)probs, (const f4*)winners, (const f4*)odds, partials, npairs);
    betting_stage2<<<1, NTHR, 0, stream>>>(partials, out, NBLK, B);
}

// Round 4
// 281.249 us; speedup vs baseline: 1.0073x; 1.0073x over previous
//
#include <hip/hip_runtime.h>
#include <math.h>

// BettingLoss: B x T (T=6) float32 inputs:
//   d_in[0] = predicted_probs, d_in[1] = true_winners, d_in[2] = market_odds
// Outputs (float32 x 3): loss, batch_profit, num_bets
//
// R4 design: every global access is a perfectly-contiguous 16B/lane
// global_load_lds (direct-to-LDS DMA). A chunk = 256 row-pairs = 768 float4
// per array. Threads then read their own 48B rows from LDS (ds_read_b128).
// This removes the 48B lane stride that was splitting each global load into
// 48 line-transactions (the r1-r3 concurrency limiter).

constexpr int T = 6;
constexpr int NTHR = 256;
constexpr int NBLK = 1024;                 // 4 blocks/CU at 36KB LDS
constexpr int CHUNK_PAIRS = 256;           // == NTHR, one pair per thread
constexpr int F4_PER_ARR = CHUNK_PAIRS * 3; // 768 float4 per array per chunk

typedef float f4 __attribute__((ext_vector_type(4)));

__device__ __forceinline__ void stage16(const f4* g, f4* l) {
    __builtin_amdgcn_global_load_lds(
        (const __attribute__((address_space(1))) void*)g,
        (__attribute__((address_space(3))) void*)l,
        16, 0, 0);
}

__global__ __launch_bounds__(NTHR) void betting_stage1(
    const f4* __restrict__ probs4,
    const f4* __restrict__ winners4,
    const f4* __restrict__ odds4,
    double* __restrict__ partials,   // [NBLK][4]: sum_bet_ep, sum_profit, sum_maxp, count
    int npairs)
{
    __shared__ f4 lp[F4_PER_ARR];
    __shared__ f4 lo[F4_PER_ARR];
    __shared__ f4 lw[F4_PER_ARR];

    const float ALPHA = 1.1f;
    const float BET = 0.02f;
    const float KEEP = 0.95f;            // 1 - commission
    const float PS = BET * KEEP;         // payout_scale

    double s_ep = 0.0, s_profit = 0.0, s_maxp = 0.0;
    int cnt = 0;

    const int t = threadIdx.x;
    const int nchunks = npairs / CHUNK_PAIRS;

    for (int c = blockIdx.x; c < nchunks; c += gridDim.x) {
        const size_t gb = (size_t)c * F4_PER_ARR;
        #pragma unroll
        for (int k = 0; k < 3; ++k) {
            const int idx = k * NTHR + t;   // lanes contiguous: 16B/lane DMA
            stage16(probs4   + gb + idx, &lp[idx]);
            stage16(odds4    + gb + idx, &lo[idx]);
            stage16(winners4 + gb + idx, &lw[idx]);
        }
        __syncthreads();   // compiler emits vmcnt(0) drain before barrier

        // this thread's pair: floats [12t, 12t+12) of each LDS array
        const float* rp = (const float*)lp + t * 12;
        const float* ro = (const float*)lo + t * 12;
        const float* rw = (const float*)lw + t * 12;
        f4 P0 = *(const f4*)(rp);  f4 P1 = *(const f4*)(rp + 4);  f4 P2 = *(const f4*)(rp + 8);
        f4 O0 = *(const f4*)(ro);  f4 O1 = *(const f4*)(ro + 4);  f4 O2 = *(const f4*)(ro + 8);
        float p[12] = {P0.x, P0.y, P0.z, P0.w, P1.x, P1.y, P1.z, P1.w, P2.x, P2.y, P2.z, P2.w};
        float o[12] = {O0.x, O0.y, O0.z, O0.w, O1.x, O1.y, O1.z, O1.w, O2.x, O2.y, O2.z, O2.w};

        #pragma unroll
        for (int rr = 0; rr < 2; ++rr) {
            const int off = rr * T;
            bool valid = false;
            float maxp = p[off];
            float best_ep = -INFINITY;
            float best_odds = 0.0f;
            int bestj = 0;
            #pragma unroll
            for (int j = 0; j < T; ++j) {
                const float oj = o[off + j];
                const float pj = p[off + j];
                valid |= (oj > 0.0f);
                maxp = fmaxf(maxp, pj);
                const float ep = (oj * ALPHA * pj - 1.0f) * PS;   // first-max argmax
                if (ep > best_ep) { best_ep = ep; best_odds = oj; bestj = j; }
            }
            s_maxp += (double)maxp;
            const bool bet = valid && (best_ep > 0.0f);
            const float wbest = rw[off + bestj];      // one ds_read_b32
            s_ep += bet ? (double)best_ep : 0.0;
            cnt += bet ? 1 : 0;
            const float profit = (wbest > 0.5f)
                ? (best_odds * ALPHA * BET - BET) * KEEP
                : -BET * KEEP;
            s_profit += bet ? (double)profit : 0.0;
        }
        __syncthreads();   // protect LDS before next chunk's staging
    }

    // tail: pairs beyond full chunks (empty for B=4194304; kept for generality)
    for (int i = nchunks * CHUNK_PAIRS + blockIdx.x * NTHR + t;
         i < npairs; i += gridDim.x * NTHR) {
        const size_t b = (size_t)i * 3;
        f4 P0 = probs4[b], P1 = probs4[b + 1], P2 = probs4[b + 2];
        f4 O0 = odds4[b],  O1 = odds4[b + 1],  O2 = odds4[b + 2];
        f4 W0 = winners4[b], W1 = winners4[b + 1], W2 = winners4[b + 2];
        float p[12] = {P0.x, P0.y, P0.z, P0.w, P1.x, P1.y, P1.z, P1.w, P2.x, P2.y, P2.z, P2.w};
        float o[12] = {O0.x, O0.y, O0.z, O0.w, O1.x, O1.y, O1.z, O1.w, O2.x, O2.y, O2.z, O2.w};
        float w[12] = {W0.x, W0.y, W0.z, W0.w, W1.x, W1.y, W1.z, W1.w, W2.x, W2.y, W2.z, W2.w};
        #pragma unroll
        for (int rr = 0; rr < 2; ++rr) {
            const int off = rr * T;
            bool valid = false;
            float maxp = p[off];
            float best_ep = -INFINITY;
            float best_odds = 0.0f, best_win = 0.0f;
            #pragma unroll
            for (int j = 0; j < T; ++j) {
                const float oj = o[off + j];
                const float pj = p[off + j];
                valid |= (oj > 0.0f);
                maxp = fmaxf(maxp, pj);
                const float ep = (oj * ALPHA * pj - 1.0f) * PS;
                if (ep > best_ep) { best_ep = ep; best_odds = oj; best_win = w[off + j]; }
            }
            s_maxp += (double)maxp;
            const bool bet = valid && (best_ep > 0.0f);
            s_ep += bet ? (double)best_ep : 0.0;
            cnt += bet ? 1 : 0;
            const float profit = (best_win > 0.5f)
                ? (best_odds * ALPHA * BET - BET) * KEEP
                : -BET * KEEP;
            s_profit += bet ? (double)profit : 0.0;
        }
    }

    // wave(64) reduction
    #pragma unroll
    for (int off = 32; off > 0; off >>= 1) {
        s_ep     += __shfl_down(s_ep, off);
        s_profit += __shfl_down(s_profit, off);
        s_maxp   += __shfl_down(s_maxp, off);
        cnt      += __shfl_down(cnt, off);
    }

    __shared__ double sm_ep[NTHR / 64];
    __shared__ double sm_pr[NTHR / 64];
    __shared__ double sm_mx[NTHR / 64];
    __shared__ int    sm_ct[NTHR / 64];
    const int lane = t & 63;
    const int wid  = t >> 6;
    if (lane == 0) {
        sm_ep[wid] = s_ep; sm_pr[wid] = s_profit; sm_mx[wid] = s_maxp; sm_ct[wid] = cnt;
    }
    __syncthreads();
    if (t == 0) {
        double t_ep = 0.0, t_pr = 0.0, t_mx = 0.0; int t_ct = 0;
        #pragma unroll
        for (int k = 0; k < NTHR / 64; ++k) {
            t_ep += sm_ep[k]; t_pr += sm_pr[k]; t_mx += sm_mx[k]; t_ct += sm_ct[k];
        }
        double* slot = partials + (size_t)blockIdx.x * 4;
        slot[0] = t_ep; slot[1] = t_pr; slot[2] = t_mx; slot[3] = (double)t_ct;
    }
}

__global__ __launch_bounds__(NTHR) void betting_stage2(
    const double* __restrict__ partials, float* __restrict__ out, int nblk, int B)
{
    double s_ep = 0.0, s_pr = 0.0, s_mx = 0.0, s_ct = 0.0;
    for (int i = threadIdx.x; i < nblk; i += blockDim.x) {
        const double* slot = partials + (size_t)i * 4;
        s_ep += slot[0]; s_pr += slot[1]; s_mx += slot[2]; s_ct += slot[3];
    }
    #pragma unroll
    for (int off = 32; off > 0; off >>= 1) {
        s_ep += __shfl_down(s_ep, off);
        s_pr += __shfl_down(s_pr, off);
        s_mx += __shfl_down(s_mx, off);
        s_ct += __shfl_down(s_ct, off);
    }
    __shared__ double sm[4][NTHR / 64];
    const int lane = threadIdx.x & 63;
    const int wid  = threadIdx.x >> 6;
    if (lane == 0) { sm[0][wid] = s_ep; sm[1][wid] = s_pr; sm[2][wid] = s_mx; sm[3][wid] = s_ct; }
    __syncthreads();
    if (threadIdx.x == 0) {
        double ep = 0.0, pr = 0.0, mx = 0.0, ct = 0.0;
        #pragma unroll
        for (int k = 0; k < NTHR / 64; ++k) { ep += sm[0][k]; pr += sm[1][k]; mx += sm[2][k]; ct += sm[3][k]; }
        bool any_bet = ct > 0.0;
        double total = any_bet ? ep : (-(mx / (double)B) * 0.1);
        out[0] = (float)(-total / (double)B);
        out[1] = (float)pr;
        out[2] = (float)ct;
    }
}

extern "C" void kernel_launch(void* const* d_in, const int* in_sizes, int n_in,
                              void* d_out, int out_size, void* d_ws, size_t ws_size,
                              hipStream_t stream) {
    const float* probs   = (const float*)d_in[0];
    const float* winners = (const float*)d_in[1];
    const float* odds    = (const float*)d_in[2];
    float* out = (float*)d_out;
    const int B = in_sizes[0] / T;
    const int npairs = B / 2;   // B = 4194304, even

    double* partials = (double*)d_ws;   // NBLK * 4 doubles = 32 KiB; every slot written each call

    betting_stage1<<<NBLK, NTHR, 0, stream>>>(
        (const f4*)probs, (const f4*)winners, (const f4*)odds, partials, npairs);
    betting_stage2<<<1, NTHR, 0, stream>>>(partials, out, NBLK, B);
}

// Round 5
// 249.376 us; speedup vs baseline: 1.1360x; 1.1278x over previous
//
#include <hip/hip_runtime.h>
#include <math.h>

// BettingLoss: B x T (T=6) float32 inputs:
//   d_in[0] = predicted_probs, d_in[1] = true_winners, d_in[2] = market_odds
// Outputs (float32 x 3): loss, batch_profit, num_bets
//
// R5: nt (nontemporal) global loads in a PERFECTLY CONTIGUOUS 16B/lane
// pattern (amplification 1.0 at the L1/TA), redistributed to 48B rows via a
// wave-private LDS region with NO barriers (per-wave DS ordering), software-
// pipelined so the next iteration's 9 loads are in flight during the current
// iteration's LDS+compute.

constexpr int T = 6;
constexpr int NTHR = 256;                 // 4 waves
constexpr int NBLK = 1024;                // 4 blocks/CU at ~36.9KB LDS
constexpr int F4_PER_WAVE = 192;          // per array: 64 pairs * 3 float4

typedef float f4 __attribute__((ext_vector_type(4)));

__device__ __forceinline__ f4 ntload(const f4* p) {
    return __builtin_nontemporal_load(p);
}

__global__ __launch_bounds__(NTHR) void betting_stage1(
    const f4* __restrict__ probs4,
    const f4* __restrict__ winners4,
    const f4* __restrict__ odds4,
    double* __restrict__ partials,   // [NBLK][4]: sum_bet_ep, sum_profit, sum_maxp, count
    int npairs)
{
    __shared__ f4 sP[4 * F4_PER_WAVE];
    __shared__ f4 sO[4 * F4_PER_WAVE];
    __shared__ f4 sW[4 * F4_PER_WAVE];

    const float ALPHA = 1.1f;
    const float BET = 0.02f;
    const float KEEP = 0.95f;            // 1 - commission
    const float PS = BET * KEEP;         // payout_scale

    double s_ep = 0.0, s_profit = 0.0, s_maxp = 0.0;
    int cnt = 0;

    const int t = threadIdx.x;
    const int lane = t & 63;
    const int w = t >> 6;

    f4* wp = sP + w * F4_PER_WAVE;
    f4* wo = sO + w * F4_PER_WAVE;
    f4* ww = sW + w * F4_PER_WAVE;

    // wave-chunk decomposition: each chunk = 64 pairs = 192 float4/array
    const long nchunks = npairs / 64;                    // 32768 for B=4M
    const long waveId = (long)blockIdx.x * 4 + w;        // 4096 waves
    const long waveStride = (long)gridDim.x * 4;

    f4 A[3], Bv[3], Wv[3];      // current chunk's loads
    f4 A2[3], B2[3], W2[3];     // next chunk's loads (pipelined)

    long c = waveId;
    if (c < nchunks) {
        const size_t gb = (size_t)c * F4_PER_WAVE;
        #pragma unroll
        for (int r = 0; r < 3; ++r) {
            A[r]  = ntload(probs4   + gb + r * 64 + lane);
            Bv[r] = ntload(odds4    + gb + r * 64 + lane);
            Wv[r] = ntload(winners4 + gb + r * 64 + lane);
        }
    }

    while (c < nchunks) {
        const long cn = c + waveStride;
        if (cn < nchunks) {
            const size_t gb = (size_t)cn * F4_PER_WAVE;
            #pragma unroll
            for (int r = 0; r < 3; ++r) {
                A2[r] = ntload(probs4   + gb + r * 64 + lane);
                B2[r] = ntload(odds4    + gb + r * 64 + lane);
                W2[r] = ntload(winners4 + gb + r * 64 + lane);
            }
        }

        // contiguous 16B/lane LDS writes (canonical conflict-free pattern)
        #pragma unroll
        for (int r = 0; r < 3; ++r) {
            wp[r * 64 + lane] = A[r];
            wo[r * 64 + lane] = Bv[r];
            ww[r * 64 + lane] = Wv[r];
        }

        // read back this lane's pair: floats [12*lane, 12*lane+12)
        const float* rp = (const float*)wp + lane * 12;
        const float* ro = (const float*)wo + lane * 12;
        const float* rw = (const float*)ww + lane * 12;
        f4 P0 = *(const f4*)(rp);  f4 P1 = *(const f4*)(rp + 4);  f4 P2 = *(const f4*)(rp + 8);
        f4 O0 = *(const f4*)(ro);  f4 O1 = *(const f4*)(ro + 4);  f4 O2 = *(const f4*)(ro + 8);
        float p[12] = {P0.x, P0.y, P0.z, P0.w, P1.x, P1.y, P1.z, P1.w, P2.x, P2.y, P2.z, P2.w};
        float o[12] = {O0.x, O0.y, O0.z, O0.w, O1.x, O1.y, O1.z, O1.w, O2.x, O2.y, O2.z, O2.w};

        #pragma unroll
        for (int rr = 0; rr < 2; ++rr) {
            const int off = rr * T;
            bool valid = false;
            float maxp = p[off];
            float best_ep = -INFINITY;
            float best_odds = 0.0f;
            int bestj = 0;
            #pragma unroll
            for (int j = 0; j < T; ++j) {
                const float oj = o[off + j];
                const float pj = p[off + j];
                valid |= (oj > 0.0f);
                maxp = fmaxf(maxp, pj);
                const float ep = (oj * ALPHA * pj - 1.0f) * PS;   // first-max argmax
                if (ep > best_ep) { best_ep = ep; best_odds = oj; bestj = j; }
            }
            s_maxp += (double)maxp;
            const bool bet = valid && (best_ep > 0.0f);
            const float wbest = rw[off + bestj];      // one ds_read_b32
            s_ep += bet ? (double)best_ep : 0.0;
            cnt += bet ? 1 : 0;
            const float profit = (wbest > 0.5f)
                ? (best_odds * ALPHA * BET - BET) * KEEP
                : -BET * KEEP;
            s_profit += bet ? (double)profit : 0.0;
        }

        #pragma unroll
        for (int r = 0; r < 3; ++r) { A[r] = A2[r]; Bv[r] = B2[r]; Wv[r] = W2[r]; }
        c = cn;
    }

    // tail: pairs beyond full wave-chunks (empty for B=4194304; generic guard)
    for (long i = nchunks * 64 + (long)blockIdx.x * NTHR + t;
         i < npairs; i += (long)gridDim.x * NTHR) {
        const size_t b = (size_t)i * 3;
        f4 P0 = probs4[b], P1 = probs4[b + 1], P2 = probs4[b + 2];
        f4 O0 = odds4[b],  O1 = odds4[b + 1],  O2 = odds4[b + 2];
        f4 W0 = winners4[b], W1 = winners4[b + 1], W2f = winners4[b + 2];
        float p[12] = {P0.x, P0.y, P0.z, P0.w, P1.x, P1.y, P1.z, P1.w, P2.x, P2.y, P2.z, P2.w};
        float o[12] = {O0.x, O0.y, O0.z, O0.w, O1.x, O1.y, O1.z, O1.w, O2.x, O2.y, O2.z, O2.w};
        float wv[12] = {W0.x, W0.y, W0.z, W0.w, W1.x, W1.y, W1.z, W1.w, W2f.x, W2f.y, W2f.z, W2f.w};
        #pragma unroll
        for (int rr = 0; rr < 2; ++rr) {
            const int off = rr * T;
            bool valid = false;
            float maxp = p[off];
            float best_ep = -INFINITY;
            float best_odds = 0.0f, best_win = 0.0f;
            #pragma unroll
            for (int j = 0; j < T; ++j) {
                const float oj = o[off + j];
                const float pj = p[off + j];
                valid |= (oj > 0.0f);
                maxp = fmaxf(maxp, pj);
                const float ep = (oj * ALPHA * pj - 1.0f) * PS;
                if (ep > best_ep) { best_ep = ep; best_odds = oj; best_win = wv[off + j]; }
            }
            s_maxp += (double)maxp;
            const bool bet = valid && (best_ep > 0.0f);
            s_ep += bet ? (double)best_ep : 0.0;
            cnt += bet ? 1 : 0;
            const float profit = (best_win > 0.5f)
                ? (best_odds * ALPHA * BET - BET) * KEEP
                : -BET * KEEP;
            s_profit += bet ? (double)profit : 0.0;
        }
    }

    // wave(64) reduction
    #pragma unroll
    for (int off = 32; off > 0; off >>= 1) {
        s_ep     += __shfl_down(s_ep, off);
        s_profit += __shfl_down(s_profit, off);
        s_maxp   += __shfl_down(s_maxp, off);
        cnt      += __shfl_down(cnt, off);
    }

    __shared__ double sm_ep[NTHR / 64];
    __shared__ double sm_pr[NTHR / 64];
    __shared__ double sm_mx[NTHR / 64];
    __shared__ int    sm_ct[NTHR / 64];
    if (lane == 0) {
        sm_ep[w] = s_ep; sm_pr[w] = s_profit; sm_mx[w] = s_maxp; sm_ct[w] = cnt;
    }
    __syncthreads();
    if (t == 0) {
        double t_ep = 0.0, t_pr = 0.0, t_mx = 0.0; int t_ct = 0;
        #pragma unroll
        for (int k = 0; k < NTHR / 64; ++k) {
            t_ep += sm_ep[k]; t_pr += sm_pr[k]; t_mx += sm_mx[k]; t_ct += sm_ct[k];
        }
        double* slot = partials + (size_t)blockIdx.x * 4;
        slot[0] = t_ep; slot[1] = t_pr; slot[2] = t_mx; slot[3] = (double)t_ct;
    }
}

__global__ __launch_bounds__(NTHR) void betting_stage2(
    const double* __restrict__ partials, float* __restrict__ out, int nblk, int B)
{
    double s_ep = 0.0, s_pr = 0.0, s_mx = 0.0, s_ct = 0.0;
    for (int i = threadIdx.x; i < nblk; i += blockDim.x) {
        const double* slot = partials + (size_t)i * 4;
        s_ep += slot[0]; s_pr += slot[1]; s_mx += slot[2]; s_ct += slot[3];
    }
    #pragma unroll
    for (int off = 32; off > 0; off >>= 1) {
        s_ep += __shfl_down(s_ep, off);
        s_pr += __shfl_down(s_pr, off);
        s_mx += __shfl_down(s_mx, off);
        s_ct += __shfl_down(s_ct, off);
    }
    __shared__ double sm[4][NTHR / 64];
    const int lane = threadIdx.x & 63;
    const int wid  = threadIdx.x >> 6;
    if (lane == 0) { sm[0][wid] = s_ep; sm[1][wid] = s_pr; sm[2][wid] = s_mx; sm[3][wid] = s_ct; }
    __syncthreads();
    if (threadIdx.x == 0) {
        double ep = 0.0, pr = 0.0, mx = 0.0, ct = 0.0;
        #pragma unroll
        for (int k = 0; k < NTHR / 64; ++k) { ep += sm[0][k]; pr += sm[1][k]; mx += sm[2][k]; ct += sm[3][k]; }
        bool any_bet = ct > 0.0;
        double total = any_bet ? ep : (-(mx / (double)B) * 0.1);
        out[0] = (float)(-total / (double)B);
        out[1] = (float)pr;
        out[2] = (float)ct;
    }
}

extern "C" void kernel_launch(void* const* d_in, const int* in_sizes, int n_in,
                              void* d_out, int out_size, void* d_ws, size_t ws_size,
                              hipStream_t stream) {
    const float* probs   = (const float*)d_in[0];
    const float* winners = (const float*)d_in[1];
    const float* odds    = (const float*)d_in[2];
    float* out = (float*)d_out;
    const int B = in_sizes[0] / T;
    const int npairs = B / 2;   // B = 4194304, even

    double* partials = (double*)d_ws;   // NBLK * 4 doubles = 32 KiB; every slot written each call

    betting_stage1<<<NBLK, NTHR, 0, stream>>>(
        (const f4*)probs, (const f4*)winners, (const f4*)odds, partials, npairs);
    betting_stage2<<<1, NTHR, 0, stream>>>(partials, out, NBLK, B);
}